// Round 2
// baseline (113.846 us; speedup 1.0000x reference)
//
#include <hip/hip_runtime.h>
#include <math.h>

#define CC 4
#define HH 64
#define WW 64
#define NN (HH*WW)
#define NTH 256
#define ITERS (NN/NTH)   // 16

__device__ __forceinline__ float block_reduce(float v, float* scratch, bool do_max) {
#pragma unroll
    for (int o = 32; o > 0; o >>= 1) {
        float other = __shfl_down(v, o, 64);
        v = do_max ? fmaxf(v, other) : (v + other);
    }
    const int wid = threadIdx.x >> 6;
    if ((threadIdx.x & 63) == 0) scratch[wid] = v;
    __syncthreads();
    if (threadIdx.x == 0) {
        float r = scratch[0];
#pragma unroll
        for (int i = 1; i < NTH / 64; ++i) r = do_max ? fmaxf(r, scratch[i]) : (r + scratch[i]);
        scratch[0] = r;
    }
    __syncthreads();
    float r = scratch[0];
    __syncthreads();   // scratch may be reused by next reduce
    return r;
}

__device__ __forceinline__ float softplusf(float x) {
    return (x > 20.f) ? x : log1pf(expf(x));
}
__device__ __forceinline__ float sigmoidf(float x) {
    return 1.f / (1.f + expf(-x));
}

__global__ __launch_bounds__(NTH)
void slam_kernel(const float* __restrict__ map_state,
                 const float* __restrict__ weight_state,
                 const float* __restrict__ key,
                 const float* __restrict__ beta,
                 const float* __restrict__ gate,
                 const float* __restrict__ shift,
                 const float* __restrict__ sharpen,
                 const float* __restrict__ add_patch_logits,
                 const float* __restrict__ erase_patch_logits,
                 float* __restrict__ out_map,
                 float* __restrict__ out_w,
                 float* __restrict__ out_rv)
{
    __shared__ float sg[NN];        // gated weights (16 KB)
    __shared__ float sp[NN];        // sharpened / final weights (16 KB)
    __shared__ float spatch[2 * CC * 9];
    __shared__ float scratch[NTH / 64];

    const int b = blockIdx.x;
    const int tid = threadIdx.x;

    // ---- per-batch scalars (redundant per-thread; all cached) ----
    const float* keyb = key + b * CC;
    float k0 = keyb[0], k1 = keyb[1], k2 = keyb[2], k3 = keyb[3];
    {
        float kn = sqrtf(k0 * k0 + k1 * k1 + k2 * k2 + k3 * k3);
        float inv = 1.f / fmaxf(kn, 1e-12f);
        k0 *= inv; k1 *= inv; k2 *= inv; k3 *= inv;
    }
    const float beta_pos  = softplusf(beta[b]) + 1e-6f;
    const float g         = sigmoidf(gate[b]);
    const float sharp_pos = 1.f + softplusf(sharpen[b]);

    // shift kernel softmax (9 values, in registers)
    float sk[9];
    {
        const float* sh = shift + b * 9;
        float m = sh[0];
#pragma unroll
        for (int i = 1; i < 9; ++i) m = fmaxf(m, sh[i]);
        float s = 0.f;
#pragma unroll
        for (int i = 0; i < 9; ++i) { sk[i] = expf(sh[i] - m); s += sk[i]; }
        float inv = 1.f / s;
#pragma unroll
        for (int i = 0; i < 9; ++i) sk[i] *= inv;
    }

    // patch sigmoids into LDS (4*9 add + 4*9 erase)
    if (tid < 2 * CC * 9) {
        float v = (tid < CC * 9) ? add_patch_logits[b * CC * 9 + tid]
                                 : erase_patch_logits[b * CC * 9 + (tid - CC * 9)];
        spatch[tid] = sigmoidf(v);
    }

    const float* mapb = map_state    + (size_t)b * CC * NN;
    const float* pwb  = weight_state + (size_t)b * NN;

    // ---- Phase 1: content softmax + gate blend ----
    float lmax = -INFINITY;
#pragma unroll
    for (int i = 0; i < ITERS; ++i) {
        int n = tid + i * NTH;
        float m0 = mapb[n], m1 = mapb[NN + n], m2 = mapb[2 * NN + n], m3 = mapb[3 * NN + n];
        float norm = sqrtf(m0 * m0 + m1 * m1 + m2 * m2 + m3 * m3);
        float inv = 1.f / fmaxf(norm, 1e-12f);
        float sim = (m0 * k0 + m1 * k1 + m2 * k2 + m3 * k3) * inv;
        float z = beta_pos * sim;
        sg[n] = z;
        lmax = fmaxf(lmax, z);
    }
    float zmax = block_reduce(lmax, scratch, true);

    float lsum = 0.f;
#pragma unroll
    for (int i = 0; i < ITERS; ++i) {
        int n = tid + i * NTH;
        float e = expf(sg[n] - zmax);
        sg[n] = e;
        lsum += e;
    }
    float Z = block_reduce(lsum, scratch, false);
    float Zinv = 1.f / Z;

#pragma unroll
    for (int i = 0; i < ITERS; ++i) {
        int n = tid + i * NTH;
        float cw = sg[n] * Zinv;
        sg[n] = g * cw + (1.f - g) * pwb[n];
    }
    __syncthreads();   // sg fully written, read cross-thread next

    // ---- Phase 2: circular 3x3 conv, sharpen, double-normalize ----
    float lsum1 = 0.f;
#pragma unroll
    for (int i = 0; i < ITERS; ++i) {
        int n = tid + i * NTH;
        int h = n >> 6, w = n & 63;
        float acc = 0.f;
#pragma unroll
        for (int dh = 0; dh < 3; ++dh) {
            int r = (h - dh + 1 + HH) & 63;
#pragma unroll
            for (int dw = 0; dw < 3; ++dw) {
                int c = (w - dw + 1 + WW) & 63;
                acc += sk[dh * 3 + dw] * sg[r * WW + c];
            }
        }
        float p = powf(fmaxf(acc, 1e-6f), sharp_pos);
        sp[n] = p;
        lsum1 += p;
    }
    float S1 = block_reduce(lsum1, scratch, false);
    float inv1 = 1.f / (S1 + 1e-6f);

    float lsum2 = 0.f;
#pragma unroll
    for (int i = 0; i < ITERS; ++i) {
        int n = tid + i * NTH;
        lsum2 += sp[n] * inv1;
    }
    float S2 = block_reduce(lsum2, scratch, false);
    float inv2 = 1.f / (S2 + 1e-6f);

#pragma unroll
    for (int i = 0; i < ITERS; ++i) {
        int n = tid + i * NTH;
        float wv = sp[n] * inv1 * inv2;
        sp[n] = wv;
        out_w[(size_t)b * NN + n] = wv;
    }
    __syncthreads();   // sp = final weights, read cross-thread next

    // ---- Phase 3: patch apply (zero-pad 3x3), map update, read vector ----
    float rv0 = 0.f, rv1 = 0.f, rv2 = 0.f, rv3 = 0.f;
#pragma unroll
    for (int i = 0; i < ITERS; ++i) {
        int n = tid + i * NTH;
        int h = n >> 6, w = n & 63;
        float wv[9];
#pragma unroll
        for (int dh = 0; dh < 3; ++dh) {
            int r = h + 1 - dh;
            bool rok = ((unsigned)r < (unsigned)HH);
#pragma unroll
            for (int dw = 0; dw < 3; ++dw) {
                int c = w + 1 - dw;
                bool ok = rok && ((unsigned)c < (unsigned)WW);
                wv[dh * 3 + dw] = ok ? sp[r * WW + c] : 0.f;
            }
        }
        float wn = sp[n];
        float rvl[CC];
#pragma unroll
        for (int ch = 0; ch < CC; ++ch) {
            float a = 0.f, e = 0.f;
#pragma unroll
            for (int t = 0; t < 9; ++t) {
                a += spatch[ch * 9 + t] * wv[t];
                e += spatch[CC * 9 + ch * 9 + t] * wv[t];
            }
            e = fminf(fmaxf(e, 0.f), 1.f);
            float mu = mapb[ch * NN + n] * (1.f - e) + a;
            out_map[(size_t)b * CC * NN + ch * NN + n] = mu;
            rvl[ch] = mu * wn;
        }
        rv0 += rvl[0]; rv1 += rvl[1]; rv2 += rvl[2]; rv3 += rvl[3];
    }
    float s0 = block_reduce(rv0, scratch, false);
    float s1 = block_reduce(rv1, scratch, false);
    float s2 = block_reduce(rv2, scratch, false);
    float s3 = block_reduce(rv3, scratch, false);
    if (tid == 0) {
        out_rv[(size_t)b * CC + 0] = s0;
        out_rv[(size_t)b * CC + 1] = s1;
        out_rv[(size_t)b * CC + 2] = s2;
        out_rv[(size_t)b * CC + 3] = s3;
    }
}

extern "C" void kernel_launch(void* const* d_in, const int* in_sizes, int n_in,
                              void* d_out, int out_size, void* d_ws, size_t ws_size,
                              hipStream_t stream) {
    const float* map_state         = (const float*)d_in[0];
    const float* weight_state      = (const float*)d_in[1];
    const float* key               = (const float*)d_in[2];
    const float* beta              = (const float*)d_in[3];
    const float* gate              = (const float*)d_in[4];
    const float* shift             = (const float*)d_in[5];
    const float* sharpen           = (const float*)d_in[6];
    // d_in[7] = erase, d_in[8] = add : unused by the reference
    const float* add_patch_logits  = (const float*)d_in[9];
    const float* erase_patch_logits= (const float*)d_in[10];

    const int B = in_sizes[1] / NN;   // weight_state is (B, H*W)

    float* out_map = (float*)d_out;
    float* out_w   = out_map + (size_t)B * CC * NN;
    float* out_rv  = out_w   + (size_t)B * NN;

    slam_kernel<<<B, NTH, 0, stream>>>(map_state, weight_state, key, beta, gate,
                                       shift, sharpen, add_patch_logits,
                                       erase_patch_logits, out_map, out_w, out_rv);
}